// Round 2
// baseline (502.014 us; speedup 1.0000x reference)
//
#include <hip/hip_runtime.h>

#define BATCH 256
#define TT 4096
#define NS 32
#define NI 8
#define NO 8
#define LCH 16
#define NCH 256   // TT / LCH
#define NSUP 16   // superchunks
#define SLEN 16   // chunks per superchunk

// ws layout (float offsets)
#define WS_M    0                        // 1024
#define WS_N0   1024                     // 256
#define WS_N1   1280                     // 256
#define WS_W    1536                     // 17*256 = 4352
#define WS_PK   5888                     // 17*1024 (ML16^k, k=0..16; [16]=ML256)
#define WS_MPOW 23296                    // 17*1024 (M^p, p=0..16)
#define WS_V    40704                    // BATCH*NCH*NS = 2097152 (v, then reused for r)
#define WS_VV   (40704 + 2097152)        // BATCH*NSUP*NS = 131072
#define WS_SS   (40704 + 2097152 + 131072) // BATCH*NSUP*NS = 131072
// total ~2.4M floats ~ 9.6 MB

__device__ __forceinline__ float dot4(float4 a, float4 b) {
    return a.x * b.x + a.y * b.y + a.z * b.z + a.w * b.w;
}
__device__ __forceinline__ float4 ld4(const float* p) { return *(const float4*)p; }

// ---------------------------------------------------------------------------
// k_pre: build M,N0,N1 (1 Dopri5 step == x' = M x + N0 u0 + N1 u1), W_j
// (chunk zero-state response weights), M powers, PK[k]=ML16^k (PK[16]=ML256).
// One block, 1024 threads.
// ---------------------------------------------------------------------------
__global__ __launch_bounds__(1024) void k_pre(const float* __restrict__ tarr,
                                              const float* __restrict__ A,
                                              const float* __restrict__ B,
                                              float* __restrict__ ws) {
    __shared__ float sA[1024], sB[256];
    __shared__ float Ka[6][1024];
    __shared__ float Kb[6][256], Kc[6][256];
    __shared__ float Sa[1024], Sb[256], Sc[256];
    __shared__ float Pq[2][1024];

    const int tid = threadIdx.x;
    const int row = tid >> 5, col = tid & 31;
    const float dt = tarr[1] - tarr[0];

    sA[tid] = A[tid];
    if (tid < 256) sB[tid] = B[tid];
    __syncthreads();
    Ka[0][tid] = sA[tid];
    if (tid < 256) { Kb[0][tid] = sB[tid]; Kc[0][tid] = 0.f; }
    __syncthreads();

    const float atab[5][5] = {
        {0.2f, 0.f, 0.f, 0.f, 0.f},
        {3.f / 40.f, 9.f / 40.f, 0.f, 0.f, 0.f},
        {44.f / 45.f, -56.f / 15.f, 32.f / 9.f, 0.f, 0.f},
        {19372.f / 6561.f, -25360.f / 2187.f, 64448.f / 6561.f, -212.f / 729.f, 0.f},
        {9017.f / 3168.f, -355.f / 33.f, 46732.f / 5247.f, 49.f / 176.f, -5103.f / 18656.f}};
    const float ctab[6] = {0.f, 0.2f, 0.3f, 0.8f, 8.f / 9.f, 1.f};

    for (int st = 1; st <= 5; ++st) {
        {
            float acc = 0.f;
            for (int j = 0; j < st; ++j) acc += atab[st - 1][j] * Ka[j][tid];
            Sa[tid] = acc;
        }
        if (tid < 256) {
            float ab = 0.f, ac = 0.f;
            for (int j = 0; j < st; ++j) {
                ab += atab[st - 1][j] * Kb[j][tid];
                ac += atab[st - 1][j] * Kc[j][tid];
            }
            Sb[tid] = ab; Sc[tid] = ac;
        }
        __syncthreads();
        {
            float acc = 0.f;
#pragma unroll
            for (int k = 0; k < NS; ++k) acc += sA[row * NS + k] * Sa[k * NS + col];
            Ka[st][tid] = sA[tid] + dt * acc;
        }
        if (tid < 256) {
            const int rb = tid >> 3, jb = tid & 7;
            float ab = 0.f, ac = 0.f;
#pragma unroll
            for (int k = 0; k < NS; ++k) {
                ab += sA[rb * NS + k] * Sb[k * NI + jb];
                ac += sA[rb * NS + k] * Sc[k * NI + jb];
            }
            Kb[st][tid] = sB[tid] + dt * ab;
            Kc[st][tid] = ctab[st] * sB[tid] + dt * ac;
        }
        __syncthreads();
    }

    const float btab[6] = {35.f / 384.f, 0.f, 500.f / 1113.f, 125.f / 192.f,
                           -2187.f / 6784.f, 11.f / 84.f};
    float m;
    {
        float acc = 0.f;
        for (int i2 = 0; i2 < 6; ++i2) acc += btab[i2] * Ka[i2][tid];
        m = dt * acc + ((row == col) ? 1.f : 0.f);
    }
    ws[WS_M + tid] = m;
    Pq[0][tid] = m;
    Sa[tid] = m;  // Sa now holds M
    ws[WS_MPOW + tid] = (row == col) ? 1.f : 0.f;
    ws[WS_MPOW + 1024 + tid] = m;
    if (tid < 256) {
        float ap = 0.f, aq = 0.f;
        for (int i2 = 0; i2 < 6; ++i2) {
            ap += btab[i2] * Kb[i2][tid];
            aq += btab[i2] * Kc[i2][tid];
        }
        const float P = dt * ap, Q = dt * aq;
        ws[WS_N0 + tid] = P - Q;
        ws[WS_N1 + tid] = Q;
        Sb[tid] = P - Q;  // N0
        Sc[tid] = Q;      // N1
    }
    __syncthreads();

    // M^p chain, p=2..16
    int cur = 0;
    for (int p = 2; p <= 16; ++p) {
        float acc = 0.f;
#pragma unroll
        for (int k = 0; k < NS; ++k) acc += Pq[cur][row * NS + k] * Sa[k * NS + col];
        Pq[cur ^ 1][tid] = acc;
        __syncthreads();
        cur ^= 1;
        ws[WS_MPOW + p * 1024 + tid] = acc;
    }
    // Pq[cur] = ML16 = M^16
    Ka[0][tid] = Pq[cur][tid];
    ws[WS_PK + tid] = (row == col) ? 1.f : 0.f;
    ws[WS_PK + 1024 + tid] = Pq[cur][tid];
    __syncthreads();
    for (int k3 = 2; k3 <= 16; ++k3) {
        float acc = 0.f;
#pragma unroll
        for (int k = 0; k < NS; ++k) acc += Pq[cur][row * NS + k] * Ka[0][k * NS + col];
        Pq[cur ^ 1][tid] = acc;
        __syncthreads();
        cur ^= 1;
        ws[WS_PK + k3 * 1024 + tid] = acc;
    }
    __syncthreads();

    // W_j = (j<=15 ? M^{15-j} N0 : 0) + (j>=1 ? M^{16-j} N1 : 0), j=0..16, 32x8 each
    for (int idx = tid; idx < 17 * 256; idx += 1024) {
        const int j = idx >> 8, e = idx & 255;
        const int r = e >> 3, cc = e & 7;
        float acc = 0.f;
        if (j <= 15) {
            const float* Mp = ws + WS_MPOW + (15 - j) * 1024 + r * NS;
#pragma unroll
            for (int k = 0; k < NS; ++k) acc += Mp[k] * Sb[k * NI + cc];
        }
        if (j >= 1) {
            const float* Mp = ws + WS_MPOW + (16 - j) * 1024 + r * NS;
#pragma unroll
            for (int k = 0; k < NS; ++k) acc += Mp[k] * Sc[k * NI + cc];
        }
        ws[WS_W + idx] = acc;
    }
}

// ---------------------------------------------------------------------------
// k_v: v[b][c] = sum_{j=0}^{16} W_j u[b][16c+j], fully parallel, one thread
// per (b,c). W staged in LDS (uniform-address broadcast reads).
// ---------------------------------------------------------------------------
__global__ __launch_bounds__(64) void k_v(const float* __restrict__ u,
                                          float* __restrict__ ws) {
    __shared__ __align__(16) float Wld[17 * 256];
    const int l = threadIdx.x;
    for (int i = l; i < 17 * 256; i += 64) Wld[i] = ws[WS_W + i];
    __syncthreads();

    const int b = blockIdx.x >> 2;
    const int c = ((blockIdx.x & 3) << 6) + l;
    if (c >= NCH - 1) return;  // v for c=0..254 only

    float acc[NS];
#pragma unroll
    for (int r = 0; r < NS; ++r) acc[r] = 0.f;

    const float* ub = u + ((size_t)b * TT + (size_t)c * LCH) * NI;
    for (int j = 0; j <= 16; ++j) {
        const float4 ua = ld4(ub + j * NI);
        const float4 ub4 = ld4(ub + j * NI + 4);
        const float4* wj = (const float4*)(Wld + j * 256);
#pragma unroll
        for (int r = 0; r < NS; ++r)
            acc[r] += dot4(wj[2 * r], ua) + dot4(wj[2 * r + 1], ub4);
    }
    float* vout = ws + WS_V + ((size_t)b * NCH + c) * NS;
#pragma unroll
    for (int r8 = 0; r8 < 8; ++r8)
        *(float4*)(vout + 4 * r8) =
            make_float4(acc[4 * r8], acc[4 * r8 + 1], acc[4 * r8 + 2], acc[4 * r8 + 3]);
}

// ---------------------------------------------------------------------------
// k_scan2a: per (b,S): r_0=0; r_k = ML16 r_{k-1} + v[16S+k-1].
// Store r_k (k=1..15) into the just-consumed v slot 16S+k-1; r_16 -> VV[b][S].
// One wave per task; lane (i=l&31, h=l>>5); only h==0 lanes carry live state.
// ---------------------------------------------------------------------------
__global__ __launch_bounds__(64) void k_scan2a(float* __restrict__ ws) {
    const int b = blockIdx.x >> 4, S = blockIdx.x & 15;
    const int l = threadIdx.x, i = l & 31, h = l >> 5;
    const float* pk1 = ws + WS_PK + 1024;  // ML16
    float mlr[16];
#pragma unroll
    for (int jj = 0; jj < 16; ++jj) mlr[jj] = pk1[i * NS + 16 * h + jj];

    float r = 0.f;
    for (int k = 1; k <= 16; ++k) {
        if (k == 16 && S == 15) break;
        const int slot = (S << 4) + k - 1;
        float p = 0.f;
#pragma unroll
        for (int jj = 0; jj < 16; ++jj) p += mlr[jj] * __shfl(r, 16 * h + jj, 64);
        p += __shfl_xor(p, 32, 64);
        float vv = 0.f;
        if (h == 0) vv = ws[WS_V + ((size_t)b * NCH + slot) * NS + i];
        r = p + vv;  // h==1 copy is dead (never a shuffle source)
        if (h == 0) {
            if (k < 16)
                ws[WS_V + ((size_t)b * NCH + slot) * NS + i] = r;
            else
                ws[WS_VV + ((size_t)(b << 4) + S) * NS + i] = r;
        }
    }
}

// ---------------------------------------------------------------------------
// k_scan2b: ssup[b][0]=x0[b]; ssup[b][S+1] = ML256 ssup[b][S] + VV[b][S].
// ---------------------------------------------------------------------------
__global__ __launch_bounds__(64) void k_scan2b(const float* __restrict__ x0,
                                               float* __restrict__ ws) {
    const int b = blockIdx.x;
    const int l = threadIdx.x, i = l & 31, h = l >> 5;
    const float* mlp = ws + WS_PK + 16 * 1024;  // ML256
    float mlr[16];
#pragma unroll
    for (int jj = 0; jj < 16; ++jj) mlr[jj] = mlp[i * NS + 16 * h + jj];

    float x = x0[b * NS + i];
    for (int S = 0; S < NSUP; ++S) {
        if (h == 0) ws[WS_SS + ((size_t)(b << 4) + S) * NS + i] = x;
        if (S == NSUP - 1) break;
        float p = 0.f;
#pragma unroll
        for (int jj = 0; jj < 16; ++jj) p += mlr[jj] * __shfl(x, 16 * h + jj, 64);
        p += __shfl_xor(p, 32, 64);
        float vv = 0.f;
        if (h == 0) vv = ws[WS_VV + ((size_t)(b << 4) + S) * NS + i];
        x = p + vv;
    }
}

// ---------------------------------------------------------------------------
// k_phase3: per (b,c) replay chunk of 16 steps from start state
// s = PK[k] ssup[b][S] + r[b][c]  (c = 16S+k), writing xs and ys.
// One wave = 8 tasks (8 consecutive b, same c); 8 lanes/task, 4 rows/lane.
// u for the chunk staged in LDS up-front (no global loads in the loop);
// y buffered in LDS, written coalesced at the end.
// ---------------------------------------------------------------------------
__global__ __launch_bounds__(64) void k_phase3(const float* __restrict__ u,
                                               float* __restrict__ ws,
                                               float* __restrict__ out,
                                               const float* __restrict__ Cc,
                                               const float* __restrict__ Dd) {
    const int c = blockIdx.x & 255;
    const int g = blockIdx.x >> 8;
    const int l = threadIdx.x, beta = l >> 3, s8 = l & 7;
    const int b = g * 8 + beta;
    const int S = c >> 4, k = c & 15;
    const int t0 = c * LCH;

    __shared__ float4 xb[2][8 * 9];
    __shared__ __align__(16) float uld[8 * 136];
    __shared__ __align__(16) float yld[8 * 136];

    // stage u: 32 float4 per task (t0..t0+15, 8 floats each)
    for (int f = l; f < 8 * 32; f += 64) {
        const int task = f >> 5, e = f & 31;
        const int bb = g * 8 + task;
        const float4 val = *((const float4*)(u + ((size_t)bb * TT + t0) * NI) + e);
        *((float4*)(uld + task * 136) + e) = val;
    }

    // start state: s = PK[k] @ ssup[b][S] + (k ? r[b][c-1-slot] : 0)
    float4 mine;
    {
        const float* pk = ws + WS_PK + k * 1024;
        const float* ss = ws + WS_SS + ((size_t)(b << 4) + S) * NS;
        float4 sv[8];
#pragma unroll
        for (int jj = 0; jj < 8; ++jj) sv[jj] = ld4(ss + 4 * jj);
        float a0 = 0.f, a1 = 0.f, a2 = 0.f, a3 = 0.f;
#pragma unroll
        for (int jj = 0; jj < 8; ++jj) {
            a0 += dot4(ld4(pk + (4 * s8 + 0) * NS + 4 * jj), sv[jj]);
            a1 += dot4(ld4(pk + (4 * s8 + 1) * NS + 4 * jj), sv[jj]);
            a2 += dot4(ld4(pk + (4 * s8 + 2) * NS + 4 * jj), sv[jj]);
            a3 += dot4(ld4(pk + (4 * s8 + 3) * NS + 4 * jj), sv[jj]);
        }
        if (k) {
            const float4 rv = ld4(ws + WS_V + ((size_t)b * NCH + c - 1) * NS + 4 * s8);
            a0 += rv.x; a1 += rv.y; a2 += rv.z; a3 += rv.w;
        }
        mine = make_float4(a0, a1, a2, a3);
    }

    // fragment caches
    const float* M = ws + WS_M;
    const float* N0 = ws + WS_N0;
    const float* N1 = ws + WS_N1;
    float4 mq[4][8];
#pragma unroll
    for (int r = 0; r < 4; ++r)
#pragma unroll
        for (int jj = 0; jj < 8; ++jj) mq[r][jj] = ld4(M + (4 * s8 + r) * NS + 4 * jj);
    float4 n0q[4][2], n1q[4][2];
#pragma unroll
    for (int r = 0; r < 4; ++r) {
        n0q[r][0] = ld4(N0 + (4 * s8 + r) * NI);
        n0q[r][1] = ld4(N0 + (4 * s8 + r) * NI + 4);
        n1q[r][0] = ld4(N1 + (4 * s8 + r) * NI);
        n1q[r][1] = ld4(N1 + (4 * s8 + r) * NI + 4);
    }
    float4 cq[8], dq[2];
#pragma unroll
    for (int jj = 0; jj < 8; ++jj) cq[jj] = ld4(Cc + s8 * NS + 4 * jj);
    dq[0] = ld4(Dd + s8 * NI);
    dq[1] = ld4(Dd + s8 * NI + 4);

    xb[0][beta * 9 + s8] = mine;
    __syncthreads();

    float4 u0a = *((const float4*)(uld + beta * 136));
    float4 u0b = *((const float4*)(uld + beta * 136) + 1);

    int cur = 0;
#pragma unroll 2
    for (int js = 0; js < LCH; ++js) {
        const int t = t0 + js;
        float4 xq[8];
#pragma unroll
        for (int jj = 0; jj < 8; ++jj) xq[jj] = xb[cur][beta * 9 + jj];

        // xs
        *(float4*)(out + ((size_t)b * TT + t) * NS + 4 * s8) = mine;
        // y -> LDS
        {
            float ya = dot4(dq[0], u0a), yb = dot4(dq[1], u0b);
#pragma unroll
            for (int jj = 0; jj < 4; ++jj) {
                ya += dot4(cq[jj], xq[jj]);
                yb += dot4(cq[jj + 4], xq[jj + 4]);
            }
            yld[beta * 136 + js * NO + s8] = ya + yb;
        }

        if (js < LCH - 1) {
            const float4 u1a = *((const float4*)(uld + beta * 136) + 2 * (js + 1));
            const float4 u1b = *((const float4*)(uld + beta * 136) + 2 * (js + 1) + 1);
            float wa[4], wb[4];
#pragma unroll
            for (int r = 0; r < 4; ++r) {
                wa[r] = dot4(n0q[r][0], u0a) + dot4(n1q[r][0], u1a);
                wb[r] = dot4(n0q[r][1], u0b) + dot4(n1q[r][1], u1b);
#pragma unroll
                for (int jj = 0; jj < 4; ++jj) {
                    wa[r] += dot4(mq[r][jj], xq[jj]);
                    wb[r] += dot4(mq[r][jj + 4], xq[jj + 4]);
                }
            }
            mine = make_float4(wa[0] + wb[0], wa[1] + wb[1], wa[2] + wb[2], wa[3] + wb[3]);
            xb[cur ^ 1][beta * 9 + s8] = mine;
            u0a = u1a;
            u0b = u1b;
        }
        __syncthreads();
        cur ^= 1;
    }

    // coalesced y writeout: 128 floats per task
    float* yout = out + (size_t)BATCH * TT * NS;
    float* ybase = yout + ((size_t)b * TT + t0) * NO;
#pragma unroll
    for (int q = 0; q < 4; ++q) {
        const float4 val = *((const float4*)(yld + beta * 136) + (s8 * 4 + q));
        *((float4*)ybase + s8 * 4 + q) = val;
    }
}

extern "C" void kernel_launch(void* const* d_in, const int* in_sizes, int n_in,
                              void* d_out, int out_size, void* d_ws, size_t ws_size,
                              hipStream_t stream) {
    const float* t = (const float*)d_in[0];
    const float* u = (const float*)d_in[1];
    const float* x0 = (const float*)d_in[2];
    const float* A = (const float*)d_in[3];
    const float* B = (const float*)d_in[4];
    const float* C = (const float*)d_in[5];
    const float* D = (const float*)d_in[6];
    float* out = (float*)d_out;
    float* ws = (float*)d_ws;

    k_pre<<<dim3(1), dim3(1024), 0, stream>>>(t, A, B, ws);
    k_v<<<dim3(BATCH * 4), dim3(64), 0, stream>>>(u, ws);
    k_scan2a<<<dim3(BATCH * NSUP), dim3(64), 0, stream>>>(ws);
    k_scan2b<<<dim3(BATCH), dim3(64), 0, stream>>>(x0, ws);
    k_phase3<<<dim3(32 * NCH), dim3(64), 0, stream>>>(u, ws, out, C, D);
}